// Round 6
// baseline (90.929 us; speedup 1.0000x reference)
//
#include <hip/hip_runtime.h>
#include <hip/hip_bf16.h>

typedef __bf16 bf16x8 __attribute__((ext_vector_type(8)));
typedef float  f32x4  __attribute__((ext_vector_type(4)));

#define B_  32
#define J_  143
#define F_  120
#define D_  256
#define L_  512
#define C_  13
#define M_  4576      // B_*J_
#define MP_ 4736      // padded rows (74*64), fe rows live at 4576..4695
#define FE0 4576
#define NK  512       // K = [hi(256) | lo(256)]
#define NN  384       // N = [Wg1c(256) | feT(120) | pad(8)]

static __device__ __forceinline__ unsigned short bits(__bf16 h) {
  return __builtin_bit_cast(unsigned short, h);
}

// exact GELU (A&S 7.1.26 erf), used only to build the LDS table (512 evals/block)
__device__ __forceinline__ float gelu_ref(float x) {
  float xs = x * 0.7071067811865476f;
  float ax = __builtin_fabsf(xs);
  float t  = __builtin_amdgcn_rcpf(__builtin_fmaf(0.3275911f, ax, 1.0f));
  float p  = __builtin_fmaf(1.061405429f, t, -1.453152027f);
  p = __builtin_fmaf(p, t, 1.421413741f);
  p = __builtin_fmaf(p, t, -0.284496736f);
  p = __builtin_fmaf(p, t, 0.254829592f);
  p = p * t;
  float e  = __expf(-ax * ax);
  float er = __builtin_fmaf(-p, e, 1.0f);
  er = (xs < 0.f) ? -er : er;
  return 0.5f * x * (1.0f + er);
}

// ---------- prepAll ----------
__global__ __launch_bounds__(256) void prepAll_kernel(
    const float* __restrict__ z, const float* __restrict__ Wl,
    const float* __restrict__ bl, const float* __restrict__ W1,
    const float* __restrict__ gamma, const float* __restrict__ beta,
    const float* __restrict__ b1, const float* __restrict__ frame_emb,
    const float* __restrict__ W2,
    float* __restrict__ base, unsigned short* __restrict__ BT,
    float* __restrict__ bW1, float* __restrict__ Sfe, float* __restrict__ Sfe2,
    unsigned short* __restrict__ W2T, float* __restrict__ zerov) {
  const int t = threadIdx.x, bid = blockIdx.x;
  const int lane = t & 63, wv = t >> 6;
  __shared__ float zs[L_];
  __shared__ float ra[4], rb[4];
  if (bid < 32) {
    zs[t]       = z[bid * L_ + t];
    zs[t + 256] = z[bid * L_ + t + 256];
    __syncthreads();
    float acc = 0.f;
    #pragma unroll 32
    for (int k = 0; k < L_; ++k) acc = __builtin_fmaf(zs[k], Wl[k * D_ + t], acc);
    base[bid * D_ + t] = acc + bl[t];
    return;
  }
  const int n = bid - 32;
  if (n < 256) {
    const float w1v = W1[t * D_ + n];
    float a = gamma[t] * w1v;
    float b = beta[t] * w1v;
    const float wg = a;
    #pragma unroll
    for (int m = 1; m < 64; m <<= 1) { a += __shfl_xor(a, m); b += __shfl_xor(b, m); }
    if (lane == 0) { ra[wv] = a; rb[wv] = b; }
    __syncthreads();
    const float cs = ra[0] + ra[1] + ra[2] + ra[3];
    if (t == 0) bW1[n] = rb[0] + rb[1] + rb[2] + rb[3] + b1[n];
    const float m = __builtin_fmaf(cs, -1.f / 256.f, wg);
    const __bf16 hi = (__bf16)m;
    const __bf16 lo = (__bf16)(m - (float)hi);
    BT[n * NK + t]       = bits(hi);
    BT[n * NK + 256 + t] = bits(lo);
  } else if (n < 376) {
    const int f = n - 256;
    const float v = frame_emb[f * D_ + t];
    float a = v, b = v * v;
    #pragma unroll
    for (int m = 1; m < 64; m <<= 1) { a += __shfl_xor(a, m); b += __shfl_xor(b, m); }
    if (lane == 0) { ra[wv] = a; rb[wv] = b; }
    __syncthreads();
    if (t == 0) {
      Sfe[f]  = ra[0] + ra[1] + ra[2] + ra[3];
      Sfe2[f] = rb[0] + rb[1] + rb[2] + rb[3];
    }
    const __bf16 hi = (__bf16)v;
    const __bf16 lo = (__bf16)(v - (float)hi);
    BT[n * NK + t]       = bits(hi);
    BT[n * NK + 256 + t] = bits(lo);
  } else if (n < 384) {
    BT[n * NK + t] = 0; BT[n * NK + 256 + t] = 0;
  } else if (n < 400) {
    const int c = n - 384;
    const float v = (c < C_) ? W2[t * C_ + c] : 0.f;
    W2T[c * D_ + t] = bits((__bf16)v);
  } else {
    zerov[t] = 0.f;
  }
}

// ---------- gemmB: PX[MP_ x NN] = A @ B with A built on the fly; Sc/Sc2 in cb==0 ----
__global__ __launch_bounds__(256, 4) void gemmB_kernel(
    const float* __restrict__ base, const float* __restrict__ joint,
    const float* __restrict__ fe, const float* __restrict__ zerov,
    const unsigned short* __restrict__ BT,
    float* __restrict__ PX, unsigned short* __restrict__ P2h,
    float* __restrict__ Sc, float* __restrict__ Sc2) {
  const int tid = threadIdx.x, lane = tid & 63, wave = tid >> 6;
  const int lrow = lane & 15, lgrp = lane >> 4;
  const int rb = blockIdx.x / 6, cb = blockIdx.x % 6;
  const int rowbase = rb * 64 + wave * 16;
  const int colbase = cb * 64;
  const int r = rowbase + lrow;

  const float *p1, *p2;
  if (r < M_) {
    const int b = r / J_, j = r - b * J_;
    p1 = base + b * D_; p2 = joint + j * D_;
  } else if (r < FE0 + F_) {
    p1 = fe + (r - FE0) * D_; p2 = zerov;
  } else {
    p1 = zerov; p2 = zerov;
  }

  const unsigned short* Bp = BT + (size_t)(colbase + lrow) * NK + lgrp * 8;
  f32x4 acc[4] = {};
  float ssum = 0.f, ssq = 0.f;
  #pragma unroll
  for (int s8 = 0; s8 < 8; ++s8) {
    const int k0 = s8 * 32 + lgrp * 8;
    const float4 ca = *(const float4*)(p1 + k0);
    const float4 cb4 = *(const float4*)(p1 + k0 + 4);
    const float4 da = *(const float4*)(p2 + k0);
    const float4 db = *(const float4*)(p2 + k0 + 4);
    const float c[8] = {ca.x + da.x, ca.y + da.y, ca.z + da.z, ca.w + da.w,
                        cb4.x + db.x, cb4.y + db.y, cb4.z + db.z, cb4.w + db.w};
    bf16x8 ahi, alo;
    #pragma unroll
    for (int e = 0; e < 8; ++e) {
      const __bf16 h = (__bf16)c[e];
      ahi[e] = h;
      alo[e] = (__bf16)(c[e] - (float)h);
    }
    if (cb == 0) {
      #pragma unroll
      for (int e = 0; e < 8; ++e) { ssum += c[e]; ssq = __builtin_fmaf(c[e], c[e], ssq); }
    }
    bf16x8 bhi[4], blo[4];
    #pragma unroll
    for (int nf = 0; nf < 4; ++nf) {
      bhi[nf] = *(const bf16x8*)(Bp + (size_t)nf * 16 * NK + s8 * 32);
      blo[nf] = *(const bf16x8*)(Bp + (size_t)nf * 16 * NK + 256 + s8 * 32);
    }
    #pragma unroll
    for (int nf = 0; nf < 4; ++nf)
      acc[nf] = __builtin_amdgcn_mfma_f32_16x16x32_bf16(ahi, bhi[nf], acc[nf], 0, 0, 0);
    #pragma unroll
    for (int nf = 0; nf < 4; ++nf)
      acc[nf] = __builtin_amdgcn_mfma_f32_16x16x32_bf16(alo, bhi[nf], acc[nf], 0, 0, 0);
    #pragma unroll
    for (int nf = 0; nf < 4; ++nf)
      acc[nf] = __builtin_amdgcn_mfma_f32_16x16x32_bf16(ahi, blo[nf], acc[nf], 0, 0, 0);
  }

  if (cb == 0) {
    ssum += __shfl_xor(ssum, 16); ssum += __shfl_xor(ssum, 32);
    ssq  += __shfl_xor(ssq, 16);  ssq  += __shfl_xor(ssq, 32);
    if (lgrp == 0) { Sc[r] = ssum; Sc2[r] = ssq; }
  }

  #pragma unroll
  for (int nf = 0; nf < 4; ++nf)
    #pragma unroll
    for (int r4 = 0; r4 < 4; ++r4) {
      const int orow = rowbase + lgrp * 4 + r4;
      const int ocol = colbase + nf * 16 + lrow;
      const float v = acc[nf][r4];
      PX[(size_t)orow * NN + ocol] = v;
      const int fr = orow - FE0;
      if (fr >= 0 && fr < F_ && ocol < 256)
        P2h[fr * 256 + ocol] = bits((__bf16)v);
    }
}

// ---------- mainC: 2 bj per block; table-gelu; GEMM2; direct stores ----
__global__ __launch_bounds__(256, 4) void mainC_kernel(
    const float* __restrict__ PX, const unsigned short* __restrict__ P2h,
    const float* __restrict__ bW1,
    const float* __restrict__ Sc, const float* __restrict__ Sc2,
    const float* __restrict__ Sfe, const float* __restrict__ Sfe2,
    const unsigned short* __restrict__ W2T, const float* __restrict__ b2,
    float* __restrict__ out) {
  __shared__ float pc[2][256], bw[256], rstdl[2][128];
  __shared__ __align__(16) unsigned short w2l[4096];   // 16x256 bf16, XOR-swizzled
  __shared__ __align__(8) float2 gtab[512];            // gelu PWL table over [-8,8]
  const int tid = threadIdx.x, lane = tid & 63, wave = tid >> 6;
  const int lrow = lane & 15, lgrp = lane >> 4;
  const int bj0 = blockIdx.x * 2;

  // --- register prefetch of q streams (issued before any barrier) ---
  const int r0 = wave * 32 + lrow, r1 = r0 + 16;
  const int f0 = r0 < F_ ? r0 : F_ - 1;
  const int f1 = r1 < F_ ? r1 : F_ - 1;
  const unsigned short* __restrict__ q0p = P2h + f0 * 256;
  const unsigned short* __restrict__ q1p = P2h + f1 * 256;
  bf16x8 qh0[8], qh1[8];
  #pragma unroll
  for (int s = 0; s < 8; ++s) {
    const int n0 = s * 32 + lgrp * 8;
    qh0[s] = *(const bf16x8*)(q0p + n0);
    qh1[s] = *(const bf16x8*)(q1p + n0);
  }

  #pragma unroll
  for (int q = 0; q < 2; ++q) pc[q][tid] = PX[(size_t)(bj0 + q) * NN + tid];
  bw[tid] = bW1[tid];
  {
    const int r = tid >> 4;
    const int b0 = tid * 32;
    const int sb = b0 ^ ((r & 7) << 4);
    *(uint4*)((char*)w2l + sb)        = *(const uint4*)((const char*)W2T + b0);
    *(uint4*)((char*)w2l + (sb ^ 16)) = *(const uint4*)((const char*)W2T + b0 + 16);
  }
  // gelu table: entry i covers x = (i-256)/32
  #pragma unroll
  for (int ii = 0; ii < 2; ++ii) {
    const int i = tid * 2 + ii;
    const float x0 = (float)(i - 256) * 0.03125f;
    const float g0 = gelu_ref(x0);
    const float g1 = gelu_ref(x0 + 0.03125f);
    gtab[i] = make_float2(g0, g1 - g0);
  }
  {
    const int q = tid >> 7;
    const int f = tid & 127;
    const int fc = f < F_ ? f : F_ - 1;
    const float X = PX[(size_t)(bj0 + q) * NN + 256 + fc];
    const float mu = (Sc[bj0 + q] + Sfe[fc]) * (1.f / 256.f);
    const float ms = __builtin_fmaf(2.f, X, Sc2[bj0 + q] + Sfe2[fc]) * (1.f / 256.f);
    rstdl[q][f] = rsqrtf(ms - mu * mu + 1e-5f);
  }
  __syncthreads();

  float rs0[2], rs1[2];
  #pragma unroll
  for (int q = 0; q < 2; ++q) { rs0[q] = rstdl[q][r0]; rs1[q] = rstdl[q][r1]; }

  f32x4 acc[2][2] = {};
  #pragma unroll
  for (int s = 0; s < 8; ++s) {
    const int n0 = s * 32 + lgrp * 8;
    const bf16x8 w2f = *(const bf16x8*)((const char*)w2l +
        ((lrow * 512 + n0 * 2) ^ ((lrow & 7) << 4)));
    float q0f[8], q1f[8], bv[8];
    #pragma unroll
    for (int e = 0; e < 8; ++e) { q0f[e] = (float)qh0[s][e]; q1f[e] = (float)qh1[s][e]; }
    const float4 ba = *(const float4*)(&bw[n0]);
    const float4 bb = *(const float4*)(&bw[n0 + 4]);
    bv[0] = ba.x; bv[1] = ba.y; bv[2] = ba.z; bv[3] = ba.w;
    bv[4] = bb.x; bv[5] = bb.y; bv[6] = bb.z; bv[7] = bb.w;
    #pragma unroll
    for (int q = 0; q < 2; ++q) {
      const float4 pa = *(const float4*)(&pc[q][n0]);
      const float4 pb = *(const float4*)(&pc[q][n0 + 4]);
      const float pv[8] = {pa.x, pa.y, pa.z, pa.w, pb.x, pb.y, pb.z, pb.w};
      bf16x8 af0, af1;
      #pragma unroll
      for (int e = 0; e < 8; ++e) {
        const float u0 = __builtin_fmaf(rs0[q], pv[e] + q0f[e], bv[e]);
        const float u1 = __builtin_fmaf(rs1[q], pv[e] + q1f[e], bv[e]);
        // table lookup: t = u*32+256, clamp, linear interp
        float t0 = __builtin_fmaf(u0, 32.f, 256.f);
        float t1 = __builtin_fmaf(u1, 32.f, 256.f);
        t0 = fminf(fmaxf(t0, 0.f), 510.999f);
        t1 = fminf(fmaxf(t1, 0.f), 510.999f);
        const int i0 = (int)t0, i1 = (int)t1;
        const float fr0 = t0 - (float)i0, fr1 = t1 - (float)i1;
        const float2 e0 = gtab[i0], e1 = gtab[i1];
        af0[e] = (__bf16)__builtin_fmaf(fr0, e0.y, e0.x);
        af1[e] = (__bf16)__builtin_fmaf(fr1, e1.y, e1.x);
      }
      acc[q][0] = __builtin_amdgcn_mfma_f32_16x16x32_bf16(af0, w2f, acc[q][0], 0, 0, 0);
      acc[q][1] = __builtin_amdgcn_mfma_f32_16x16x32_bf16(af1, w2f, acc[q][1], 0, 0, 0);
    }
  }

  // ---- direct epilogue: acc[q][mf][r4] is (c=lrow, f=wave*32+mf*16+lgrp*4+r4) ----
  if (lrow < C_) {
    const float bias = b2[lrow];
    #pragma unroll
    for (int q = 0; q < 2; ++q)
      #pragma unroll
      for (int mf = 0; mf < 2; ++mf) {
        const int f = wave * 32 + mf * 16 + lgrp * 4;
        if (f < F_) {
          float4 v;
          v.x = acc[q][mf][0] + bias;
          v.y = acc[q][mf][1] + bias;
          v.z = acc[q][mf][2] + bias;
          v.w = acc[q][mf][3] + bias;
          *(float4*)(out + (size_t)(bj0 + q) * (C_ * F_) + lrow * F_ + f) = v;
        }
      }
  }
}

extern "C" void kernel_launch(void* const* d_in, const int* in_sizes, int n_in,
                              void* d_out, int out_size, void* d_ws, size_t ws_size,
                              hipStream_t stream) {
  const float* z         = (const float*)d_in[0];
  const float* W_latent  = (const float*)d_in[1];
  const float* b_latent  = (const float*)d_in[2];
  const float* joint_emb = (const float*)d_in[3];
  const float* frame_emb = (const float*)d_in[4];
  const float* ln_g      = (const float*)d_in[5];
  const float* ln_b      = (const float*)d_in[6];
  const float* W1        = (const float*)d_in[7];
  const float* b1        = (const float*)d_in[8];
  const float* W2        = (const float*)d_in[9];
  const float* b2        = (const float*)d_in[10];
  float* out = (float*)d_out;

  char* ws = (char*)d_ws;
  float*          base  = (float*)(ws + 0);              // 32 KB
  unsigned short* W2T   = (unsigned short*)(ws + 32768); // 8 KB
  float*          bW1   = (float*)(ws + 40960);          // 1 KB
  float*          Sfe   = (float*)(ws + 41984);          // 0.5 KB
  float*          Sfe2  = (float*)(ws + 42496);          // 0.5 KB
  float*          Sc    = (float*)(ws + 43008);          // 18.5 KB
  float*          Sc2   = (float*)(ws + 61952);          // 18.5 KB
  float*          zerov = (float*)(ws + 80896);          // 1 KB
  unsigned short* BT    = (unsigned short*)(ws + 81920); // 384 KB
  unsigned short* P2h   = (unsigned short*)(ws + 700416);// 60 KB
  float*          PX    = (float*)(ws + 8388608);        // 7.0 MB

  prepAll_kernel<<<433, 256, 0, stream>>>(z, W_latent, b_latent, W1, ln_g, ln_b, b1,
                                          frame_emb, W2, base, BT, bW1, Sfe, Sfe2,
                                          W2T, zerov);
  gemmB_kernel<<<444, 256, 0, stream>>>(base, joint_emb, frame_emb, zerov, BT,
                                        PX, P2h, Sc, Sc2);
  mainC_kernel<<<M_ / 2, 256, 0, stream>>>(PX, P2h, bW1, Sc, Sc2, Sfe, Sfe2, W2T, b2, out);
}

// Round 7
// 85.619 us; speedup vs baseline: 1.0620x; 1.0620x over previous
//
#include <hip/hip_runtime.h>
#include <hip/hip_bf16.h>

typedef __bf16 bf16x8 __attribute__((ext_vector_type(8)));
typedef float  f32x4  __attribute__((ext_vector_type(4)));
typedef float  f32x2  __attribute__((ext_vector_type(2)));

#define B_  32
#define J_  143
#define F_  120
#define D_  256
#define L_  512
#define C_  13
#define M_  4576      // B_*J_
#define MP_ 4736      // padded rows (74*64), fe rows live at 4576..4695
#define FE0 4576
#define NK  512       // K = [hi(256) | lo(256)]
#define NN  384       // N = [Wg1c(256) | feT(120) | pad(8)]

static __device__ __forceinline__ unsigned short bits(__bf16 h) {
  return __builtin_bit_cast(unsigned short, h);
}

// packed tanh-GELU (ln2 folded): u * rcp(1 + exp2(u*(c1 + c2*u^2))), 2 lanes at once
__device__ __forceinline__ f32x2 gelu2(f32x2 u) {
  f32x2 x2 = u * u;
  f32x2 t  = u * (x2 * -0.1029432f + -2.3022082f);
  f32x2 e;
  e.x = __builtin_amdgcn_exp2f(t.x);
  e.y = __builtin_amdgcn_exp2f(t.y);
  f32x2 d = e + 1.0f;
  f32x2 r;
  r.x = __builtin_amdgcn_rcpf(d.x);
  r.y = __builtin_amdgcn_rcpf(d.y);
  return u * r;
}

// ---------- prepAll ----------
__global__ __launch_bounds__(256) void prepAll_kernel(
    const float* __restrict__ z, const float* __restrict__ Wl,
    const float* __restrict__ bl, const float* __restrict__ W1,
    const float* __restrict__ gamma, const float* __restrict__ beta,
    const float* __restrict__ b1, const float* __restrict__ frame_emb,
    const float* __restrict__ W2,
    float* __restrict__ base, unsigned short* __restrict__ BT,
    float* __restrict__ bW1, float* __restrict__ Sfe, float* __restrict__ Sfe2,
    unsigned short* __restrict__ W2T, float* __restrict__ zerov) {
  const int t = threadIdx.x, bid = blockIdx.x;
  const int lane = t & 63, wv = t >> 6;
  __shared__ float zs[L_];
  __shared__ float ra[4], rb[4];
  if (bid < 32) {
    zs[t]       = z[bid * L_ + t];
    zs[t + 256] = z[bid * L_ + t + 256];
    __syncthreads();
    float acc = 0.f;
    #pragma unroll 32
    for (int k = 0; k < L_; ++k) acc = __builtin_fmaf(zs[k], Wl[k * D_ + t], acc);
    base[bid * D_ + t] = acc + bl[t];
    return;
  }
  const int n = bid - 32;
  if (n < 256) {
    const float w1v = W1[t * D_ + n];
    float a = gamma[t] * w1v;
    float b = beta[t] * w1v;
    const float wg = a;
    #pragma unroll
    for (int m = 1; m < 64; m <<= 1) { a += __shfl_xor(a, m); b += __shfl_xor(b, m); }
    if (lane == 0) { ra[wv] = a; rb[wv] = b; }
    __syncthreads();
    const float cs = ra[0] + ra[1] + ra[2] + ra[3];
    if (t == 0) bW1[n] = rb[0] + rb[1] + rb[2] + rb[3] + b1[n];
    const float m = __builtin_fmaf(cs, -1.f / 256.f, wg);
    const __bf16 hi = (__bf16)m;
    const __bf16 lo = (__bf16)(m - (float)hi);
    BT[n * NK + t]       = bits(hi);
    BT[n * NK + 256 + t] = bits(lo);
  } else if (n < 376) {
    const int f = n - 256;
    const float v = frame_emb[f * D_ + t];
    float a = v, b = v * v;
    #pragma unroll
    for (int m = 1; m < 64; m <<= 1) { a += __shfl_xor(a, m); b += __shfl_xor(b, m); }
    if (lane == 0) { ra[wv] = a; rb[wv] = b; }
    __syncthreads();
    if (t == 0) {
      Sfe[f]  = ra[0] + ra[1] + ra[2] + ra[3];
      Sfe2[f] = rb[0] + rb[1] + rb[2] + rb[3];
    }
    const __bf16 hi = (__bf16)v;
    const __bf16 lo = (__bf16)(v - (float)hi);
    BT[n * NK + t]       = bits(hi);
    BT[n * NK + 256 + t] = bits(lo);
  } else if (n < 384) {
    BT[n * NK + t] = 0; BT[n * NK + 256 + t] = 0;
  } else if (n < 400) {
    const int c = n - 384;
    const float v = (c < C_) ? W2[t * C_ + c] : 0.f;
    W2T[c * D_ + t] = bits((__bf16)v);
  } else {
    zerov[t] = 0.f;
  }
}

// ---------- gemmB: PX[MP_ x NN] = A @ B, 64-row x 32-col tiles (888 blocks) ----
__global__ __launch_bounds__(256, 4) void gemmB_kernel(
    const float* __restrict__ base, const float* __restrict__ joint,
    const float* __restrict__ fe, const float* __restrict__ zerov,
    const unsigned short* __restrict__ BT,
    float* __restrict__ PX, unsigned short* __restrict__ P2h,
    float* __restrict__ Sc, float* __restrict__ Sc2) {
  const int tid = threadIdx.x, lane = tid & 63, wave = tid >> 6;
  const int lrow = lane & 15, lgrp = lane >> 4;
  const int rb = blockIdx.x / 12, cb = blockIdx.x % 12;
  const int rowbase = rb * 64 + wave * 16;
  const int colbase = cb * 32;
  const int r = rowbase + lrow;

  const float *p1, *p2;
  if (r < M_) {
    const int b = r / J_, j = r - b * J_;
    p1 = base + b * D_; p2 = joint + j * D_;
  } else if (r < FE0 + F_) {
    p1 = fe + (r - FE0) * D_; p2 = zerov;
  } else {
    p1 = zerov; p2 = zerov;
  }

  const unsigned short* Bp = BT + (size_t)(colbase + lrow) * NK + lgrp * 8;
  f32x4 acc[2] = {};
  float ssum = 0.f, ssq = 0.f;
  #pragma unroll
  for (int s8 = 0; s8 < 8; ++s8) {
    const int k0 = s8 * 32 + lgrp * 8;
    const float4 ca = *(const float4*)(p1 + k0);
    const float4 cb4 = *(const float4*)(p1 + k0 + 4);
    const float4 da = *(const float4*)(p2 + k0);
    const float4 db = *(const float4*)(p2 + k0 + 4);
    const float c[8] = {ca.x + da.x, ca.y + da.y, ca.z + da.z, ca.w + da.w,
                        cb4.x + db.x, cb4.y + db.y, cb4.z + db.z, cb4.w + db.w};
    bf16x8 ahi, alo;
    #pragma unroll
    for (int e = 0; e < 8; ++e) {
      const __bf16 h = (__bf16)c[e];
      ahi[e] = h;
      alo[e] = (__bf16)(c[e] - (float)h);
    }
    if (cb == 0) {
      #pragma unroll
      for (int e = 0; e < 8; ++e) { ssum += c[e]; ssq = __builtin_fmaf(c[e], c[e], ssq); }
    }
    bf16x8 bhi[2], blo[2];
    #pragma unroll
    for (int nf = 0; nf < 2; ++nf) {
      bhi[nf] = *(const bf16x8*)(Bp + (size_t)nf * 16 * NK + s8 * 32);
      blo[nf] = *(const bf16x8*)(Bp + (size_t)nf * 16 * NK + 256 + s8 * 32);
    }
    #pragma unroll
    for (int nf = 0; nf < 2; ++nf) {
      acc[nf] = __builtin_amdgcn_mfma_f32_16x16x32_bf16(ahi, bhi[nf], acc[nf], 0, 0, 0);
      acc[nf] = __builtin_amdgcn_mfma_f32_16x16x32_bf16(alo, bhi[nf], acc[nf], 0, 0, 0);
      acc[nf] = __builtin_amdgcn_mfma_f32_16x16x32_bf16(ahi, blo[nf], acc[nf], 0, 0, 0);
    }
  }

  if (cb == 0) {
    ssum += __shfl_xor(ssum, 16); ssum += __shfl_xor(ssum, 32);
    ssq  += __shfl_xor(ssq, 16);  ssq  += __shfl_xor(ssq, 32);
    if (lgrp == 0) { Sc[r] = ssum; Sc2[r] = ssq; }
  }

  #pragma unroll
  for (int nf = 0; nf < 2; ++nf)
    #pragma unroll
    for (int r4 = 0; r4 < 4; ++r4) {
      const int orow = rowbase + lgrp * 4 + r4;
      const int ocol = colbase + nf * 16 + lrow;
      const float v = acc[nf][r4];
      PX[(size_t)orow * NN + ocol] = v;
      const int fr = orow - FE0;
      if (fr >= 0 && fr < F_ && ocol < 256)
        P2h[fr * 256 + ocol] = bits((__bf16)v);
    }
}

// ---------- mainC: 2 bj per block; packed-f32 gelu; GEMM2; direct stores ----
__global__ __launch_bounds__(256, 6) void mainC_kernel(
    const float* __restrict__ PX, const unsigned short* __restrict__ P2h,
    const float* __restrict__ bW1,
    const float* __restrict__ Sc, const float* __restrict__ Sc2,
    const float* __restrict__ Sfe, const float* __restrict__ Sfe2,
    const unsigned short* __restrict__ W2T, const float* __restrict__ b2,
    float* __restrict__ out) {
  __shared__ float pc[2][256], bw[256], rstdl[2][128];
  __shared__ __align__(16) unsigned short w2l[4096];   // 16x256 bf16, XOR-swizzled
  const int tid = threadIdx.x, lane = tid & 63, wave = tid >> 6;
  const int lrow = lane & 15, lgrp = lane >> 4;
  const int bj0 = blockIdx.x * 2;

  #pragma unroll
  for (int q = 0; q < 2; ++q) pc[q][tid] = PX[(size_t)(bj0 + q) * NN + tid];
  bw[tid] = bW1[tid];
  {
    const int r = tid >> 4;
    const int b0 = tid * 32;
    const int sb = b0 ^ ((r & 7) << 4);
    *(uint4*)((char*)w2l + sb)        = *(const uint4*)((const char*)W2T + b0);
    *(uint4*)((char*)w2l + (sb ^ 16)) = *(const uint4*)((const char*)W2T + b0 + 16);
  }
  {
    const int q = tid >> 7;
    const int f = tid & 127;
    const int fc = f < F_ ? f : F_ - 1;
    const float X = PX[(size_t)(bj0 + q) * NN + 256 + fc];
    const float mu = (Sc[bj0 + q] + Sfe[fc]) * (1.f / 256.f);
    const float ms = __builtin_fmaf(2.f, X, Sc2[bj0 + q] + Sfe2[fc]) * (1.f / 256.f);
    rstdl[q][f] = rsqrtf(ms - mu * mu + 1e-5f);
  }
  __syncthreads();

  const int r0 = wave * 32 + lrow, r1 = r0 + 16;
  const int f0 = r0 < F_ ? r0 : F_ - 1;
  const int f1 = r1 < F_ ? r1 : F_ - 1;
  f32x2 RS0[2], RS1[2];
  #pragma unroll
  for (int q = 0; q < 2; ++q) {
    const float a = rstdl[q][r0], b = rstdl[q][r1];
    RS0[q].x = a; RS0[q].y = a;
    RS1[q].x = b; RS1[q].y = b;
  }
  const unsigned short* __restrict__ q0p = P2h + f0 * 256 + lgrp * 8;
  const unsigned short* __restrict__ q1p = P2h + f1 * 256 + lgrp * 8;

  // 1-ahead q prefetch (16 VGPRs)
  bf16x8 qc0 = *(const bf16x8*)(q0p);
  bf16x8 qc1 = *(const bf16x8*)(q1p);

  f32x4 acc[2][2] = {};
  #pragma unroll
  for (int s = 0; s < 8; ++s) {
    const int n0 = s * 32 + lgrp * 8;
    bf16x8 qn0, qn1;
    if (s < 7) {
      qn0 = *(const bf16x8*)(q0p + (s + 1) * 32);
      qn1 = *(const bf16x8*)(q1p + (s + 1) * 32);
    }
    const bf16x8 w2f = *(const bf16x8*)((const char*)w2l +
        ((lrow * 512 + n0 * 2) ^ ((lrow & 7) << 4)));
    bf16x8 af[2][2];
    #pragma unroll
    for (int ep = 0; ep < 4; ++ep) {
      const int e0 = 2 * ep;
      f32x2 Q0, Q1, BV;
      Q0.x = (float)qc0[e0]; Q0.y = (float)qc0[e0 + 1];
      Q1.x = (float)qc1[e0]; Q1.y = (float)qc1[e0 + 1];
      BV = *(const f32x2*)(&bw[n0 + e0]);
      #pragma unroll
      for (int q = 0; q < 2; ++q) {
        const f32x2 P = *(const f32x2*)(&pc[q][n0 + e0]);
        const f32x2 U0 = __builtin_elementwise_fma(RS0[q], P + Q0, BV);
        const f32x2 U1 = __builtin_elementwise_fma(RS1[q], P + Q1, BV);
        const f32x2 G0 = gelu2(U0);
        const f32x2 G1 = gelu2(U1);
        af[q][0][e0] = (__bf16)G0.x; af[q][0][e0 + 1] = (__bf16)G0.y;
        af[q][1][e0] = (__bf16)G1.x; af[q][1][e0 + 1] = (__bf16)G1.y;
      }
    }
    #pragma unroll
    for (int q = 0; q < 2; ++q) {
      acc[q][0] = __builtin_amdgcn_mfma_f32_16x16x32_bf16(af[q][0], w2f, acc[q][0], 0, 0, 0);
      acc[q][1] = __builtin_amdgcn_mfma_f32_16x16x32_bf16(af[q][1], w2f, acc[q][1], 0, 0, 0);
    }
    qc0 = qn0; qc1 = qn1;
  }

  // ---- direct epilogue: acc[q][mf][r4] is (c=lrow, f=wave*32+mf*16+lgrp*4+r4) ----
  if (lrow < C_) {
    const float bias = b2[lrow];
    #pragma unroll
    for (int q = 0; q < 2; ++q)
      #pragma unroll
      for (int mf = 0; mf < 2; ++mf) {
        const int f = wave * 32 + mf * 16 + lgrp * 4;
        if (f < F_) {
          float4 v;
          v.x = acc[q][mf][0] + bias;
          v.y = acc[q][mf][1] + bias;
          v.z = acc[q][mf][2] + bias;
          v.w = acc[q][mf][3] + bias;
          *(float4*)(out + (size_t)(bj0 + q) * (C_ * F_) + lrow * F_ + f) = v;
        }
      }
  }
}

extern "C" void kernel_launch(void* const* d_in, const int* in_sizes, int n_in,
                              void* d_out, int out_size, void* d_ws, size_t ws_size,
                              hipStream_t stream) {
  const float* z         = (const float*)d_in[0];
  const float* W_latent  = (const float*)d_in[1];
  const float* b_latent  = (const float*)d_in[2];
  const float* joint_emb = (const float*)d_in[3];
  const float* frame_emb = (const float*)d_in[4];
  const float* ln_g      = (const float*)d_in[5];
  const float* ln_b      = (const float*)d_in[6];
  const float* W1        = (const float*)d_in[7];
  const float* b1        = (const float*)d_in[8];
  const float* W2        = (const float*)d_in[9];
  const float* b2        = (const float*)d_in[10];
  float* out = (float*)d_out;

  char* ws = (char*)d_ws;
  float*          base  = (float*)(ws + 0);              // 32 KB
  unsigned short* W2T   = (unsigned short*)(ws + 32768); // 8 KB
  float*          bW1   = (float*)(ws + 40960);          // 1 KB
  float*          Sfe   = (float*)(ws + 41984);          // 0.5 KB
  float*          Sfe2  = (float*)(ws + 42496);          // 0.5 KB
  float*          Sc    = (float*)(ws + 43008);          // 18.5 KB
  float*          Sc2   = (float*)(ws + 61952);          // 18.5 KB
  float*          zerov = (float*)(ws + 80896);          // 1 KB
  unsigned short* BT    = (unsigned short*)(ws + 81920); // 384 KB
  unsigned short* P2h   = (unsigned short*)(ws + 700416);// 60 KB
  float*          PX    = (float*)(ws + 8388608);        // 7.0 MB

  prepAll_kernel<<<433, 256, 0, stream>>>(z, W_latent, b_latent, W1, ln_g, ln_b, b1,
                                          frame_emb, W2, base, BT, bW1, Sfe, Sfe2,
                                          W2T, zerov);
  gemmB_kernel<<<888, 256, 0, stream>>>(base, joint_emb, frame_emb, zerov, BT,
                                        PX, P2h, Sc, Sc2);
  mainC_kernel<<<M_ / 2, 256, 0, stream>>>(PX, P2h, bW1, Sc, Sc2, Sfe, Sfe2, W2T, b2, out);
}

// Round 9
// 83.856 us; speedup vs baseline: 1.0843x; 1.0210x over previous
//
#include <hip/hip_runtime.h>
#include <hip/hip_bf16.h>
#include <hip/hip_cooperative_groups.h>

namespace cg = cooperative_groups;

typedef __bf16 bf16x8 __attribute__((ext_vector_type(8)));
typedef float  f32x4  __attribute__((ext_vector_type(4)));
typedef float  f32x2  __attribute__((ext_vector_type(2)));

#define B_  32
#define J_  143
#define F_  120
#define D_  256
#define L_  512
#define C_  13
#define M_  4576      // B_*J_
#define MP_ 4736      // padded rows (74*64), fe rows live at 4576..4695
#define FE0 4576
#define NK  512       // K = [hi(256) | lo(256)]
#define NN  384       // N = [Wg1c(256) | feT(120) | pad(8)]
#define GRID_  763    // cooperative grid: 3 pairs per block (763*3 >= 2288)
#define PAIRS_ 2288   // M_/2

static __device__ __forceinline__ unsigned short bits(__bf16 h) {
  return __builtin_bit_cast(unsigned short, h);
}

// packed tanh-GELU (ln2 folded): u * rcp(1 + exp2(u*(c1 + c2*u^2)))
__device__ __forceinline__ f32x2 gelu2(f32x2 u) {
  f32x2 x2 = u * u;
  f32x2 t  = u * (x2 * -0.1029432f + -2.3022082f);
  f32x2 e;
  e.x = __builtin_amdgcn_exp2f(t.x);
  e.y = __builtin_amdgcn_exp2f(t.y);
  f32x2 d = e + 1.0f;
  f32x2 r;
  r.x = __builtin_amdgcn_rcpf(d.x);
  r.y = __builtin_amdgcn_rcpf(d.y);
  return u * r;
}

// phase: 0 = cooperative all-phases; 1/2/3 = run only that phase (normal launch)
__global__ __launch_bounds__(256, 3) void fused_kernel(
    int phase,
    const float* __restrict__ z, const float* __restrict__ Wl,
    const float* __restrict__ bl, const float* __restrict__ joint,
    const float* __restrict__ fe, const float* __restrict__ gamma,
    const float* __restrict__ beta, const float* __restrict__ W1,
    const float* __restrict__ b1, const float* __restrict__ W2,
    const float* __restrict__ b2,
    float* __restrict__ base, unsigned short* __restrict__ BT,
    float* __restrict__ bW1, float* __restrict__ Sfe, float* __restrict__ Sfe2,
    unsigned short* __restrict__ W2T, float* __restrict__ zerov,
    float* __restrict__ PX, float* __restrict__ Sc, float* __restrict__ Sc2,
    float* __restrict__ out) {
  __shared__ float zs[L_];
  __shared__ float ra[4], rb[4];
  __shared__ float pc[2][256], bw[256], rstdl[2][128];
  __shared__ __align__(16) unsigned short w2l[4096];   // 16x256 bf16, XOR-swizzled

  const int tid  = threadIdx.x;
  const int lane = tid & 63, wv = tid >> 6;
  const int lrow = lane & 15, lgrp = lane >> 4;
  const int bid  = blockIdx.x;
  const bool coop = (phase == 0);

  // ================= phase 1: prep (433 units) =================
  if (coop || phase == 1) {
    if (bid < 32) {
      zs[tid]       = z[bid * L_ + tid];
      zs[tid + 256] = z[bid * L_ + tid + 256];
      __syncthreads();
      float acc = 0.f;
      #pragma unroll 32
      for (int k = 0; k < L_; ++k) acc = __builtin_fmaf(zs[k], Wl[k * D_ + tid], acc);
      base[bid * D_ + tid] = acc + bl[tid];
    } else if (bid < 433) {
      const int n = bid - 32;
      if (n < 256) {
        const float w1v = W1[tid * D_ + n];
        float a = gamma[tid] * w1v;
        float b = beta[tid] * w1v;
        const float wg = a;
        #pragma unroll
        for (int m = 1; m < 64; m <<= 1) { a += __shfl_xor(a, m); b += __shfl_xor(b, m); }
        if (lane == 0) { ra[wv] = a; rb[wv] = b; }
        __syncthreads();
        const float cs = ra[0] + ra[1] + ra[2] + ra[3];
        if (tid == 0) bW1[n] = rb[0] + rb[1] + rb[2] + rb[3] + b1[n];
        const float m = __builtin_fmaf(cs, -1.f / 256.f, wg);
        const __bf16 hi = (__bf16)m;
        const __bf16 lo = (__bf16)(m - (float)hi);
        BT[n * NK + tid]       = bits(hi);
        BT[n * NK + 256 + tid] = bits(lo);
      } else if (n < 376) {
        const int f = n - 256;
        const float v = fe[f * D_ + tid];
        float a = v, b = v * v;
        #pragma unroll
        for (int m = 1; m < 64; m <<= 1) { a += __shfl_xor(a, m); b += __shfl_xor(b, m); }
        if (lane == 0) { ra[wv] = a; rb[wv] = b; }
        __syncthreads();
        if (tid == 0) {
          Sfe[f]  = ra[0] + ra[1] + ra[2] + ra[3];
          Sfe2[f] = rb[0] + rb[1] + rb[2] + rb[3];
        }
        const __bf16 hi = (__bf16)v;
        const __bf16 lo = (__bf16)(v - (float)hi);
        BT[n * NK + tid]       = bits(hi);
        BT[n * NK + 256 + tid] = bits(lo);
      } else if (n < 384) {
        BT[n * NK + tid] = 0; BT[n * NK + 256 + tid] = 0;
      } else if (n < 400) {
        const int c = n - 384;
        const float v = (c < C_) ? W2[tid * C_ + c] : 0.f;
        W2T[c * D_ + tid] = bits((__bf16)v);
      } else {
        zerov[tid] = 0.f;
      }
    }
  }
  if (coop) cg::this_grid().sync();

  // ================= phase 2: gemmB (444 units, 64x64 tiles) =================
  if ((coop || phase == 2) && bid < 444) {
    const int rb_ = bid / 6, cb_ = bid % 6;
    const int rowbase = rb_ * 64 + wv * 16;
    const int colbase = cb_ * 64;
    const int r = rowbase + lrow;

    const float *p1, *p2;
    if (r < M_) {
      const int b = r / J_, j = r - b * J_;
      p1 = base + b * D_; p2 = joint + j * D_;
    } else if (r < FE0 + F_) {
      p1 = fe + (r - FE0) * D_; p2 = zerov;
    } else {
      p1 = zerov; p2 = zerov;
    }

    const unsigned short* Bp = BT + (size_t)(colbase + lrow) * NK + lgrp * 8;
    f32x4 acc[4] = {};
    float ssum = 0.f, ssq = 0.f;
    #pragma unroll
    for (int s8 = 0; s8 < 8; ++s8) {
      const int k0 = s8 * 32 + lgrp * 8;
      const float4 ca = *(const float4*)(p1 + k0);
      const float4 cb4 = *(const float4*)(p1 + k0 + 4);
      const float4 da = *(const float4*)(p2 + k0);
      const float4 db = *(const float4*)(p2 + k0 + 4);
      const float c[8] = {ca.x + da.x, ca.y + da.y, ca.z + da.z, ca.w + da.w,
                          cb4.x + db.x, cb4.y + db.y, cb4.z + db.z, cb4.w + db.w};
      bf16x8 ahi, alo;
      #pragma unroll
      for (int e = 0; e < 8; ++e) {
        const __bf16 h = (__bf16)c[e];
        ahi[e] = h;
        alo[e] = (__bf16)(c[e] - (float)h);
      }
      if (cb_ == 0) {
        #pragma unroll
        for (int e = 0; e < 8; ++e) { ssum += c[e]; ssq = __builtin_fmaf(c[e], c[e], ssq); }
      }
      bf16x8 bhi[4], blo[4];
      #pragma unroll
      for (int nf = 0; nf < 4; ++nf) {
        bhi[nf] = *(const bf16x8*)(Bp + (size_t)nf * 16 * NK + s8 * 32);
        blo[nf] = *(const bf16x8*)(Bp + (size_t)nf * 16 * NK + 256 + s8 * 32);
      }
      #pragma unroll
      for (int nf = 0; nf < 4; ++nf)
        acc[nf] = __builtin_amdgcn_mfma_f32_16x16x32_bf16(ahi, bhi[nf], acc[nf], 0, 0, 0);
      #pragma unroll
      for (int nf = 0; nf < 4; ++nf)
        acc[nf] = __builtin_amdgcn_mfma_f32_16x16x32_bf16(alo, bhi[nf], acc[nf], 0, 0, 0);
      #pragma unroll
      for (int nf = 0; nf < 4; ++nf)
        acc[nf] = __builtin_amdgcn_mfma_f32_16x16x32_bf16(ahi, blo[nf], acc[nf], 0, 0, 0);
    }

    if (cb_ == 0) {
      ssum += __shfl_xor(ssum, 16); ssum += __shfl_xor(ssum, 32);
      ssq  += __shfl_xor(ssq, 16);  ssq  += __shfl_xor(ssq, 32);
      if (lgrp == 0) { Sc[r] = ssum; Sc2[r] = ssq; }
    }

    #pragma unroll
    for (int nf = 0; nf < 4; ++nf)
      #pragma unroll
      for (int r4 = 0; r4 < 4; ++r4)
        PX[(size_t)(rowbase + lgrp * 4 + r4) * NN + colbase + nf * 16 + lrow] = acc[nf][r4];
  }
  if (coop) cg::this_grid().sync();

  // ================= phase 3: mainC (pair-stride loop) =================
  if (coop || phase == 3) {
    bw[tid] = bW1[tid];
    {
      const int rr = tid >> 4;
      const int b0 = tid * 32;
      const int sb = b0 ^ ((rr & 7) << 4);
      *(uint4*)((char*)w2l + sb)        = *(const uint4*)((const char*)W2T + b0);
      *(uint4*)((char*)w2l + (sb ^ 16)) = *(const uint4*)((const char*)W2T + b0 + 16);
    }
    const float bias = (lrow < C_) ? b2[lrow] : 0.f;

    const int r0 = wv * 32 + lrow, r1 = r0 + 16;
    const int f0 = r0 < F_ ? r0 : F_ - 1;
    const int f1 = r1 < F_ ? r1 : F_ - 1;
    const float* __restrict__ q0p = PX + (size_t)(FE0 + f0) * NN + lgrp * 8;
    const float* __restrict__ q1p = PX + (size_t)(FE0 + f1) * NN + lgrp * 8;

    for (int pair = bid; pair < PAIRS_; pair += (int)gridDim.x) {
      const int bj0 = pair * 2;
      __syncthreads();   // orders w2l/bw writes (first iter) and pc/rstdl reuse

      #pragma unroll
      for (int q = 0; q < 2; ++q) pc[q][tid] = PX[(size_t)(bj0 + q) * NN + tid];
      {
        const int q = tid >> 7;
        const int f = tid & 127;
        const int fc = f < F_ ? f : F_ - 1;
        const float X = PX[(size_t)(bj0 + q) * NN + 256 + fc];
        const float mu = (Sc[bj0 + q] + Sfe[fc]) * (1.f / 256.f);
        const float ms = __builtin_fmaf(2.f, X, Sc2[bj0 + q] + Sfe2[fc]) * (1.f / 256.f);
        rstdl[q][f] = rsqrtf(ms - mu * mu + 1e-5f);
      }
      __syncthreads();

      f32x2 RS0[2], RS1[2];
      #pragma unroll
      for (int q = 0; q < 2; ++q) {
        const float a = rstdl[q][r0], b = rstdl[q][r1];
        RS0[q].x = a; RS0[q].y = a;
        RS1[q].x = b; RS1[q].y = b;
      }

      // 1-ahead f32 q prefetch
      float4 qa0 = *(const float4*)(q0p), qa1 = *(const float4*)(q0p + 4);
      float4 qb0 = *(const float4*)(q1p), qb1 = *(const float4*)(q1p + 4);

      f32x4 acc[2][2] = {};
      #pragma unroll
      for (int s = 0; s < 8; ++s) {
        const int n0 = s * 32 + lgrp * 8;
        float4 na0, na1, nb0, nb1;
        if (s < 7) {
          na0 = *(const float4*)(q0p + (s + 1) * 32);
          na1 = *(const float4*)(q0p + (s + 1) * 32 + 4);
          nb0 = *(const float4*)(q1p + (s + 1) * 32);
          nb1 = *(const float4*)(q1p + (s + 1) * 32 + 4);
        }
        const bf16x8 w2f = *(const bf16x8*)((const char*)w2l +
            ((lrow * 512 + n0 * 2) ^ ((lrow & 7) << 4)));
        const float q0v[8] = {qa0.x, qa0.y, qa0.z, qa0.w, qa1.x, qa1.y, qa1.z, qa1.w};
        const float q1v[8] = {qb0.x, qb0.y, qb0.z, qb0.w, qb1.x, qb1.y, qb1.z, qb1.w};
        bf16x8 af[2][2];
        #pragma unroll
        for (int ep = 0; ep < 4; ++ep) {
          const int e0 = 2 * ep;
          f32x2 Q0, Q1, BV;
          Q0.x = q0v[e0]; Q0.y = q0v[e0 + 1];
          Q1.x = q1v[e0]; Q1.y = q1v[e0 + 1];
          BV = *(const f32x2*)(&bw[n0 + e0]);
          #pragma unroll
          for (int q = 0; q < 2; ++q) {
            const f32x2 P = *(const f32x2*)(&pc[q][n0 + e0]);
            const f32x2 U0 = __builtin_elementwise_fma(RS0[q], P + Q0, BV);
            const f32x2 U1 = __builtin_elementwise_fma(RS1[q], P + Q1, BV);
            const f32x2 G0 = gelu2(U0);
            const f32x2 G1 = gelu2(U1);
            af[q][0][e0] = (__bf16)G0.x; af[q][0][e0 + 1] = (__bf16)G0.y;
            af[q][1][e0] = (__bf16)G1.x; af[q][1][e0 + 1] = (__bf16)G1.y;
          }
        }
        #pragma unroll
        for (int q = 0; q < 2; ++q) {
          acc[q][0] = __builtin_amdgcn_mfma_f32_16x16x32_bf16(af[q][0], w2f, acc[q][0], 0, 0, 0);
          acc[q][1] = __builtin_amdgcn_mfma_f32_16x16x32_bf16(af[q][1], w2f, acc[q][1], 0, 0, 0);
        }
        qa0 = na0; qa1 = na1; qb0 = nb0; qb1 = nb1;
      }

      // direct epilogue: acc[q][mf][r4] is (c=lrow, f=wv*32+mf*16+lgrp*4+r4)
      if (lrow < C_) {
        #pragma unroll
        for (int q = 0; q < 2; ++q)
          #pragma unroll
          for (int mf = 0; mf < 2; ++mf) {
            const int f = wv * 32 + mf * 16 + lgrp * 4;
            if (f < F_) {
              float4 v;
              v.x = acc[q][mf][0] + bias;
              v.y = acc[q][mf][1] + bias;
              v.z = acc[q][mf][2] + bias;
              v.w = acc[q][mf][3] + bias;
              *(float4*)(out + (size_t)(bj0 + q) * (C_ * F_) + lrow * F_ + f) = v;
            }
          }
      }
    }
  }
}

extern "C" void kernel_launch(void* const* d_in, const int* in_sizes, int n_in,
                              void* d_out, int out_size, void* d_ws, size_t ws_size,
                              hipStream_t stream) {
  const float* z     = (const float*)d_in[0];
  const float* Wl    = (const float*)d_in[1];
  const float* bl    = (const float*)d_in[2];
  const float* joint = (const float*)d_in[3];
  const float* fe    = (const float*)d_in[4];
  const float* gamma = (const float*)d_in[5];
  const float* beta  = (const float*)d_in[6];
  const float* W1    = (const float*)d_in[7];
  const float* b1    = (const float*)d_in[8];
  const float* W2    = (const float*)d_in[9];
  const float* b2    = (const float*)d_in[10];
  float* out = (float*)d_out;

  char* ws = (char*)d_ws;
  float*          base  = (float*)(ws + 0);              // 32 KB
  unsigned short* W2T   = (unsigned short*)(ws + 32768); // 8 KB
  float*          bW1   = (float*)(ws + 40960);          // 1 KB
  float*          Sfe   = (float*)(ws + 41984);          // 0.5 KB
  float*          Sfe2  = (float*)(ws + 42496);          // 0.5 KB
  float*          Sc    = (float*)(ws + 43008);          // 18.5 KB
  float*          Sc2   = (float*)(ws + 61952);          // 18.5 KB
  float*          zerov = (float*)(ws + 80896);          // 1 KB
  unsigned short* BT    = (unsigned short*)(ws + 81920); // 384 KB
  float*          PX    = (float*)(ws + 8388608);        // 7.0 MB

  int phase0 = 0;
  void* args[] = {
    (void*)&phase0,
    (void*)&z, (void*)&Wl, (void*)&bl, (void*)&joint, (void*)&fe,
    (void*)&gamma, (void*)&beta, (void*)&W1, (void*)&b1, (void*)&W2, (void*)&b2,
    (void*)&base, (void*)&BT, (void*)&bW1, (void*)&Sfe, (void*)&Sfe2,
    (void*)&W2T, (void*)&zerov, (void*)&PX, (void*)&Sc, (void*)&Sc2, (void*)&out
  };

  int maxB = 0;
  hipError_t qe = hipOccupancyMaxActiveBlocksPerMultiprocessor(&maxB, fused_kernel, 256, 0);
  const bool coopOK = (qe == hipSuccess) && (maxB >= 3);

  if (coopOK) {
    hipLaunchCooperativeKernel((const void*)fused_kernel, dim3(GRID_), dim3(256),
                               args, 0, stream);
  } else {
    fused_kernel<<<433, 256, 0, stream>>>(1, z, Wl, bl, joint, fe, gamma, beta, W1,
        b1, W2, b2, base, BT, bW1, Sfe, Sfe2, W2T, zerov, PX, Sc, Sc2, out);
    fused_kernel<<<444, 256, 0, stream>>>(2, z, Wl, bl, joint, fe, gamma, beta, W1,
        b1, W2, b2, base, BT, bW1, Sfe, Sfe2, W2T, zerov, PX, Sc, Sc2, out);
    fused_kernel<<<PAIRS_, 256, 0, stream>>>(3, z, Wl, bl, joint, fe, gamma, beta, W1,
        b1, W2, b2, base, BT, bW1, Sfe, Sfe2, W2T, zerov, PX, Sc, Sc2, out);
  }
}